// Round 3
// baseline (230.950 us; speedup 1.0000x reference)
//
#include <hip/hip_runtime.h>

// YOLO v1 loss, B=16384, S=7, C=30. 192.7 MB read -> 1 float.
// R1: per-thread strided loads, 73.8us. R2: LDS staging via VGPRs, 76.6us —
// latency-serialized load->vmcnt(0)->ds_write chains (~29K cyc/block).
// R3: global_load_lds width-16 DMA (m97 pattern): 15 independent DMAs/wave,
// no VGPR round-trip; 128 cells/block -> 30.7KB LDS -> 5 blocks/CU.

#define NS 7
#define NC 30
#define CPB 128                      // cells per block
#define BLOCK 128                    // 2 waves
#define CHUNK_FLOATS (CPB * NC)      // 3840 floats = 15360 B per array per block

typedef __attribute__((address_space(1))) const float global_float;
typedef __attribute__((address_space(3))) float lds_float;

__global__ __launch_bounds__(BLOCK) void yolo_loss_kernel(
    const float* __restrict__ pred,
    const float* __restrict__ targ,
    float* __restrict__ out, float inv_B)
{
    const float STEP = 1.0f / 7.0f;
    const float L_COORD = 5.0f;
    const float L_NOOBJ = 0.5f;

    // [0..3840): pred cells of this block, [3840..7680): targ cells
    __shared__ float sbuf[2 * CHUNK_FLOATS];   // 30720 B

    const int tid = threadIdx.x;
    const int wave = tid >> 6;        // 0 or 1
    const int lane = tid & 63;

    // DMA staging: wave 0 -> pred chunk, wave 1 -> targ chunk.
    // Each of 15 instrs moves 1024 B: lane i reads g+lane*16, HW writes
    // LDS wave-uniform base + lane*16.
    {
        const size_t base_bytes = (size_t)blockIdx.x * (CHUNK_FLOATS * 4);
        const char* gbase = (const char*)(wave == 0 ? pred : targ) + base_bytes
                          + (size_t)lane * 16;
        char* lbase = (char*)sbuf + wave * (CHUNK_FLOATS * 4);
        #pragma unroll
        for (int i = 0; i < 15; ++i) {
            __builtin_amdgcn_global_load_lds(
                (global_float*)(gbase + i * 1024),
                (lds_float*)(lbase + i * 1024),
                16, 0, 0);
        }
    }
    __syncthreads();   // drains vmcnt before LDS reads

    // Per-cell math from LDS
    const int cell = blockIdx.x * CPB + tid;
    const int j = cell % NS;          // second spatial axis -> gj (y offset)
    const int i = (cell / NS) % NS;   // first spatial axis  -> gi (x offset)
    const float gi = (float)i;
    const float gj = (float)j;

    float p[NC], t[NC];
    {
        const float2* lp2 = (const float2*)(sbuf + tid * NC);
        const float2* lt2 = (const float2*)(sbuf + CHUNK_FLOATS + tid * NC);
        #pragma unroll
        for (int k = 0; k < NC / 2; ++k) {
            float2 v = lp2[k]; p[2 * k] = v.x; p[2 * k + 1] = v.y;
            float2 u = lt2[k]; t[2 * k] = u.x; t[2 * k + 1] = u.y;
        }
    }

    // _convert_box for target, pred box1 (ch 0:4), pred box2 (ch 5:9)
    float ta, tb, tc, td;
    {
        float cx = (t[0] + gi) * STEP;
        float cy = (t[1] + gj) * STEP;
        ta = fmaxf(cx - t[2] * 0.5f, 0.0f);
        tb = fmaxf(cy - t[3] * 0.5f, 0.0f);
        tc = fminf(cx + t[2] * 0.5f, 1.0f);
        td = fminf(cy + t[3] * 0.5f, 1.0f);
    }
    float q1, w1, e1, r1;
    {
        float cx = (p[0] + gi) * STEP;
        float cy = (p[1] + gj) * STEP;
        q1 = fmaxf(cx - p[2] * 0.5f, 0.0f);
        w1 = fmaxf(cy - p[3] * 0.5f, 0.0f);
        e1 = fminf(cx + p[2] * 0.5f, 1.0f);
        r1 = fminf(cy + p[3] * 0.5f, 1.0f);
    }
    float q2, w2, e2, r2;
    {
        float cx = (p[5] + gi) * STEP;
        float cy = (p[6] + gj) * STEP;
        q2 = fmaxf(cx - p[7] * 0.5f, 0.0f);
        w2 = fmaxf(cy - p[8] * 0.5f, 0.0f);
        e2 = fminf(cx + p[7] * 0.5f, 1.0f);
        r2 = fminf(cy + p[8] * 0.5f, 1.0f);
    }

    float tarea = (td - tb) * (tc - ta);
    // _iou: inter NOT clamped; iou = inter>0 ? inter/(union+1e-5) : 0
    float iou1, iou2;
    {
        float minx = fmaxf(ta, q1), miny = fmaxf(tb, w1);
        float maxx = fminf(tc, e1), maxy = fminf(td, r1);
        float inter = (maxy - miny) * (maxx - minx);
        float uni = (e1 - q1) * (r1 - w1) + tarea - inter;
        iou1 = (inter > 0.0f) ? inter / (uni + 1e-5f) : 0.0f;
    }
    {
        float minx = fmaxf(ta, q2), miny = fmaxf(tb, w2);
        float maxx = fminf(tc, e2), maxy = fminf(td, r2);
        float inter = (maxy - miny) * (maxx - minx);
        float uni = (e2 - q2) * (r2 - w2) + tarea - inter;
        iou2 = (inter > 0.0f) ? inter / (uni + 1e-5f) : 0.0f;
    }

    bool sel2 = (iou1 <= iou2);
    float conf_t = sel2 ? iou2 : iou1;
    float px = sel2 ? p[5] : p[0];
    float py = sel2 ? p[6] : p[1];
    float pw = sel2 ? p[7] : p[2];
    float ph = sel2 ? p[8] : p[3];
    float pconf = sel2 ? p[9] : p[4];

    float obj = (t[4] > 0.0f) ? 1.0f : 0.0f;
    float noobj = (t[4] == 0.0f) ? 1.0f : 0.0f;

    float dx = px - t[0], dy = py - t[1];
    float dw = pw - t[2], dh = ph - t[3];
    float coord = dx * dx + dy * dy + dw * dw + dh * dh;

    float dc = pconf - conf_t;
    float obj_loss = dc * dc;

    float cls = 0.0f;
    #pragma unroll
    for (int k = 10; k < NC; ++k) {
        float d = p[k] - t[k];
        cls += d * d;
    }

    float d4 = p[4] - t[4];
    float d9 = p[9] - t[9];
    float noobj_loss = d4 * d4 + d9 * d9;

    float lsum = obj * (obj_loss + L_COORD * coord + cls) + L_NOOBJ * noobj * noobj_loss;

    // wave(64) shuffle reduce
    #pragma unroll
    for (int off = 32; off > 0; off >>= 1)
        lsum += __shfl_down(lsum, off, 64);

    __shared__ float wsum[2];
    if (lane == 0) wsum[wave] = lsum;
    __syncthreads();
    if (tid == 0) {
        atomicAdd(out, (wsum[0] + wsum[1]) * inv_B);
    }
}

extern "C" void kernel_launch(void* const* d_in, const int* in_sizes, int n_in,
                              void* d_out, int out_size, void* d_ws, size_t ws_size,
                              hipStream_t stream) {
    const float* pred = (const float*)d_in[0];
    const float* targ = (const float*)d_in[1];
    float* out = (float*)d_out;

    const int B = 16384;
    const int n_cells = B * NS * NS;        // 802816 = 6272 * 128
    const float inv_B = 1.0f / (float)B;

    hipMemsetAsync(out, 0, sizeof(float) * out_size, stream);

    const int grid = n_cells / CPB;         // 6272
    yolo_loss_kernel<<<grid, BLOCK, 0, stream>>>(pred, targ, out, inv_B);
}

// Round 4
// 208.944 us; speedup vs baseline: 1.1053x; 1.1053x over previous
//
#include <hip/hip_runtime.h>

// YOLO v1 loss, B=16384, S=7, C=30. 192.7 MB read -> 1 float.
// R1 73.8us strided loads; R2 76.6us LDS staging; R3 95.7us DMA staging.
// R3 diagnosis: duration scales with #blocks = #atomicAdds to ONE address
// (R2->R3: +3136 atomics -> +19us; L3-warm dispatch still 72us). Same-address
// device-scope RMWs serialize at the coherence point; kernel-completion drains
// the queue with no resident waves (occ 17%, all pipes idle).
// R4: zero atomics. Stage 1: per-block partial -> plain store to d_ws.
// Stage 2: one block reduces 6272 partials -> out[0] (also replaces memset).

#define NS 7
#define NC 30
#define CPB 128                      // cells per block
#define BLOCK 128                    // 2 waves
#define CHUNK_FLOATS (CPB * NC)      // 3840 floats = 15360 B per array per block
#define GRID1 6272                   // 802816 / 128

typedef __attribute__((address_space(1))) const float global_float;
typedef __attribute__((address_space(3))) float lds_float;

__global__ __launch_bounds__(BLOCK) void yolo_loss_stage1(
    const float* __restrict__ pred,
    const float* __restrict__ targ,
    float* __restrict__ partials)
{
    const float STEP = 1.0f / 7.0f;
    const float L_COORD = 5.0f;
    const float L_NOOBJ = 0.5f;

    // [0..3840): pred cells of this block, [3840..7680): targ cells
    __shared__ float sbuf[2 * CHUNK_FLOATS];   // 30720 B -> 5 blocks/CU

    const int tid = threadIdx.x;
    const int wave = tid >> 6;        // 0 or 1
    const int lane = tid & 63;

    // DMA staging: wave 0 -> pred chunk, wave 1 -> targ chunk.
    // 15 instrs x 1024 B each; LDS dest = wave-uniform base + lane*16.
    {
        const size_t base_bytes = (size_t)blockIdx.x * (CHUNK_FLOATS * 4);
        const char* gbase = (const char*)(wave == 0 ? pred : targ) + base_bytes
                          + (size_t)lane * 16;
        char* lbase = (char*)sbuf + wave * (CHUNK_FLOATS * 4);
        #pragma unroll
        for (int i = 0; i < 15; ++i) {
            __builtin_amdgcn_global_load_lds(
                (global_float*)(gbase + i * 1024),
                (lds_float*)(lbase + i * 1024),
                16, 0, 0);
        }
    }
    __syncthreads();   // drains vmcnt before LDS reads

    // Per-cell math from LDS
    const int cell = blockIdx.x * CPB + tid;
    const int j = cell % NS;          // second spatial axis -> gj (y offset)
    const int i = (cell / NS) % NS;   // first spatial axis  -> gi (x offset)
    const float gi = (float)i;
    const float gj = (float)j;

    float p[NC], t[NC];
    {
        const float2* lp2 = (const float2*)(sbuf + tid * NC);
        const float2* lt2 = (const float2*)(sbuf + CHUNK_FLOATS + tid * NC);
        #pragma unroll
        for (int k = 0; k < NC / 2; ++k) {
            float2 v = lp2[k]; p[2 * k] = v.x; p[2 * k + 1] = v.y;
            float2 u = lt2[k]; t[2 * k] = u.x; t[2 * k + 1] = u.y;
        }
    }

    // _convert_box for target, pred box1 (ch 0:4), pred box2 (ch 5:9)
    float ta, tb, tc, td;
    {
        float cx = (t[0] + gi) * STEP;
        float cy = (t[1] + gj) * STEP;
        ta = fmaxf(cx - t[2] * 0.5f, 0.0f);
        tb = fmaxf(cy - t[3] * 0.5f, 0.0f);
        tc = fminf(cx + t[2] * 0.5f, 1.0f);
        td = fminf(cy + t[3] * 0.5f, 1.0f);
    }
    float q1, w1, e1, r1;
    {
        float cx = (p[0] + gi) * STEP;
        float cy = (p[1] + gj) * STEP;
        q1 = fmaxf(cx - p[2] * 0.5f, 0.0f);
        w1 = fmaxf(cy - p[3] * 0.5f, 0.0f);
        e1 = fminf(cx + p[2] * 0.5f, 1.0f);
        r1 = fminf(cy + p[3] * 0.5f, 1.0f);
    }
    float q2, w2, e2, r2;
    {
        float cx = (p[5] + gi) * STEP;
        float cy = (p[6] + gj) * STEP;
        q2 = fmaxf(cx - p[7] * 0.5f, 0.0f);
        w2 = fmaxf(cy - p[8] * 0.5f, 0.0f);
        e2 = fminf(cx + p[7] * 0.5f, 1.0f);
        r2 = fminf(cy + p[8] * 0.5f, 1.0f);
    }

    float tarea = (td - tb) * (tc - ta);
    // _iou: inter NOT clamped; iou = inter>0 ? inter/(union+1e-5) : 0
    float iou1, iou2;
    {
        float minx = fmaxf(ta, q1), miny = fmaxf(tb, w1);
        float maxx = fminf(tc, e1), maxy = fminf(td, r1);
        float inter = (maxy - miny) * (maxx - minx);
        float uni = (e1 - q1) * (r1 - w1) + tarea - inter;
        iou1 = (inter > 0.0f) ? inter / (uni + 1e-5f) : 0.0f;
    }
    {
        float minx = fmaxf(ta, q2), miny = fmaxf(tb, w2);
        float maxx = fminf(tc, e2), maxy = fminf(td, r2);
        float inter = (maxy - miny) * (maxx - minx);
        float uni = (e2 - q2) * (r2 - w2) + tarea - inter;
        iou2 = (inter > 0.0f) ? inter / (uni + 1e-5f) : 0.0f;
    }

    bool sel2 = (iou1 <= iou2);
    float conf_t = sel2 ? iou2 : iou1;
    float px = sel2 ? p[5] : p[0];
    float py = sel2 ? p[6] : p[1];
    float pw = sel2 ? p[7] : p[2];
    float ph = sel2 ? p[8] : p[3];
    float pconf = sel2 ? p[9] : p[4];

    float obj = (t[4] > 0.0f) ? 1.0f : 0.0f;
    float noobj = (t[4] == 0.0f) ? 1.0f : 0.0f;

    float dx = px - t[0], dy = py - t[1];
    float dw = pw - t[2], dh = ph - t[3];
    float coord = dx * dx + dy * dy + dw * dw + dh * dh;

    float dc = pconf - conf_t;
    float obj_loss = dc * dc;

    float cls = 0.0f;
    #pragma unroll
    for (int k = 10; k < NC; ++k) {
        float d = p[k] - t[k];
        cls += d * d;
    }

    float d4 = p[4] - t[4];
    float d9 = p[9] - t[9];
    float noobj_loss = d4 * d4 + d9 * d9;

    float lsum = obj * (obj_loss + L_COORD * coord + cls) + L_NOOBJ * noobj * noobj_loss;

    // wave(64) shuffle reduce
    #pragma unroll
    for (int off = 32; off > 0; off >>= 1)
        lsum += __shfl_down(lsum, off, 64);

    __shared__ float wsum[2];
    if (lane == 0) wsum[wave] = lsum;
    __syncthreads();
    if (tid == 0) {
        partials[blockIdx.x] = wsum[0] + wsum[1];   // plain store, NO atomic
    }
}

__global__ __launch_bounds__(256) void yolo_loss_stage2(
    const float* __restrict__ partials, float* __restrict__ out, float inv_B)
{
    const int tid = threadIdx.x;
    float s = 0.0f;
    for (int k = tid; k < GRID1; k += 256)
        s += partials[k];

    #pragma unroll
    for (int off = 32; off > 0; off >>= 1)
        s += __shfl_down(s, off, 64);

    __shared__ float wsum[4];
    int lane = tid & 63;
    int wid = tid >> 6;
    if (lane == 0) wsum[wid] = s;
    __syncthreads();
    if (tid == 0)
        out[0] = (wsum[0] + wsum[1] + wsum[2] + wsum[3]) * inv_B;
}

extern "C" void kernel_launch(void* const* d_in, const int* in_sizes, int n_in,
                              void* d_out, int out_size, void* d_ws, size_t ws_size,
                              hipStream_t stream) {
    const float* pred = (const float*)d_in[0];
    const float* targ = (const float*)d_in[1];
    float* out = (float*)d_out;
    float* partials = (float*)d_ws;          // 6272 floats = 25 KB scratch

    const float inv_B = 1.0f / 16384.0f;

    yolo_loss_stage1<<<GRID1, BLOCK, 0, stream>>>(pred, targ, partials);
    yolo_loss_stage2<<<1, 256, 0, stream>>>(partials, out, inv_B);
}